// Round 11
// baseline (279.528 us; speedup 1.0000x reference)
//
#include <hip/hip_runtime.h>
#include <hip/hip_cooperative_groups.h>
#include <math.h>

namespace cg = cooperative_groups;

#define TWO_PI_F 6.2831853071795864769f
#define LUT_N    2048
#define LUT_SCALE 170.66666667f   // 2048/12
#define LUT_STEP  0.005859375f    // 12/2048 (exact)

static __device__ __forceinline__ float sin_rev(float x) {   // sin(2*pi*x)
#if __has_builtin(__builtin_amdgcn_sinf)
    return __builtin_amdgcn_sinf(x);
#else
    return __sinf(TWO_PI_F * x);
#endif
}

// accurate branchless CDF: 0.5*(1+erf(x/sqrt2)), A&S 7.1.26 (|err|<=1.5e-7)
static __device__ __forceinline__ float cdf_acc(float v) {
    const float y  = v * 0.70710678118654752f;
    const float ay = fabsf(y);
    const float t  = __builtin_amdgcn_rcpf(fmaf(0.3275911f, ay, 1.0f));
    const float e  = __builtin_amdgcn_exp2f(y * y * -1.4426950408889634f);
    float p = fmaf(1.061405429f, t, -1.453152027f);
    p = fmaf(p, t, 1.421413741f);
    p = fmaf(p, t, -0.284496736f);
    p = fmaf(p, t, 0.254829592f);
    const float erf_abs = 1.0f - p * t * e;
    const float erf_v   = __builtin_copysignf(erf_abs, v);
    return fmaf(0.5f, erf_v, 0.5f);
}
static __device__ __forceinline__ float gelu_s(float v) { return v * cdf_acc(v); }

// LDS-LUT gelu: x * lerp(t_i, t_i+dt_i)
static __device__ __forceinline__ float gelu_lut(float x, const float2* __restrict__ lut) {
    float f = __builtin_amdgcn_fmed3f(fmaf(x, LUT_SCALE, 1024.0f), 0.0f, 2047.5f);
    float fr = __builtin_amdgcn_fractf(f);
    float2 e = lut[(int)f];
    return x * fmaf(fr, e.y, e.x);
}

static __device__ __forceinline__ void build_lut(float2* lut, int tid) {
    for (int i = tid; i < LUT_N; i += 256) {
        float x0 = fmaf((float)i, LUT_STEP, -6.0f);
        float t0 = cdf_acc(x0);
        float t1 = cdf_acc(x0 + LUT_STEP);
        lut[i] = make_float2(t0, t1 - t0);
    }
}

// cst layout: [2]=sr [8..23]=tfs0(sr*tf0) [24..39]=tfs1(0.5*sr*tf1)
//             [40..71]=W1e(8x4) [72..79]=b1e(8)
// Weight-only fold of the constant internal path; called by one block.
// Contains __syncthreads — must be entered by the whole block.
static __device__ void fold_weights(
    int tid,
    const float* __restrict__ r_tf, const float* __restrict__ r_tc,
    const float* __restrict__ i_w,  const float* __restrict__ i_b,
    const float* __restrict__ i_tf, const float* __restrict__ i_tc,
    const float* __restrict__ W_ri, const float* __restrict__ b_ri,
    const float* __restrict__ W_ir, const float* __restrict__ b_ir,
    const float* __restrict__ flow_gate, const float* __restrict__ mem,
    const float* __restrict__ W_o1, const float* __restrict__ b_o1,
    float* __restrict__ cst,
    float* s_hc, float* s_cv, float* s_m4)
{
    if (tid < 64) {
        const int j = tid & 15;
        float base = i_b[j];
#pragma unroll
        for (int k = 0; k < 16; ++k) base = fmaf(i_w[j*16 + k], mem[k], base);
        float corr = 0.f;
#pragma unroll
        for (int n = 0; n < 3; ++n) {
            float lo = 0.f;
#pragma unroll
            for (int k = 0; k < 16; ++k) lo = fmaf(i_tf[n*256 + j*16 + k], mem[k], lo);
            float a = fabsf(lo);
            a += __shfl_xor(a, 1); a += __shfl_xor(a, 2);
            a += __shfl_xor(a, 4); a += __shfl_xor(a, 8);
            const float mean = a * (1.0f/16.0f);
            const float phase = TWO_PI_F * (float)(n+1) * lo / (mean + 1e-8f);
            corr = fmaf(sinf(phase), lo / (float)(n+1), corr);
        }
        const float sc = 1.0f / (1.0f + expf(-i_tc[0]));
        const float t = fmaf(sc, corr, base);
        float mu = t;
        mu += __shfl_xor(mu, 1); mu += __shfl_xor(mu, 2);
        mu += __shfl_xor(mu, 4); mu += __shfl_xor(mu, 8);
        mu *= (1.0f/16.0f);
        const float d = t - mu;
        float v = d*d;
        v += __shfl_xor(v, 1); v += __shfl_xor(v, 2);
        v += __shfl_xor(v, 4); v += __shfl_xor(v, 8);
        v *= (1.0f/16.0f);
        const float h = gelu_s(d * rsqrtf(v + 1e-5f));
        if (tid < 16) s_hc[j] = h;
    }
    __syncthreads();
    const float g  = 1.0f / (1.0f + expf(-flow_gate[0]));
    const float sr = 1.0f / (1.0f + expf(-r_tc[0]));
    if (tid < 4) {
        float acc = 0.f;
#pragma unroll
        for (int m = 0; m < 16; ++m)
            acc = fmaf(W_ir[tid*16 + m], fmaf(g, b_ri[m], s_hc[m]), acc);
        s_cv[tid] = g * (acc + b_ir[tid]);
    }
    if (tid < 16) {
        const int l = tid >> 2, j = tid & 3;
        float M = 0.f;
#pragma unroll
        for (int m = 0; m < 16; ++m) M = fmaf(W_ir[l*16 + m], W_ri[m*4 + j], M);
        s_m4[tid] = g * g * M;
        cst[8  + tid] = sr * r_tf[tid];             // tfs0
        cst[24 + tid] = 0.5f * sr * r_tf[16 + tid]; // tfs1
    }
    if (tid == 0) cst[2] = sr;
    __syncthreads();
    if (tid < 32) {   // W1e = W_o1 @ (I + M4)
        const int h = tid >> 2, j = tid & 3;
        float we = 0.f;
#pragma unroll
        for (int l = 0; l < 4; ++l)
            we = fmaf(W_o1[h*4 + l], ((l == j) ? 1.0f : 0.0f) + s_m4[l*4 + j], we);
        cst[40 + tid] = we;
    }
    if (tid < 8) {    // b1e = b_o1 + W_o1 @ cvec
        float be = b_o1[tid];
#pragma unroll
        for (int l = 0; l < 4; ++l) be = fmaf(W_o1[tid*4 + l], s_cv[l], be);
        cst[72 + tid] = be;
    }
}

// row tail shared by fused phase-D / fallback k_main
static __device__ __forceinline__ void row_pipeline(
    const float xv[6],
    const float* __restrict__ W_in, const float* __restrict__ b_in,
    const float* __restrict__ r_w,  const float* __restrict__ r_b,
    const float* __restrict__ W_o2, const float* __restrict__ b_o2,
    const float* __restrict__ cst, const float2* __restrict__ s_lut,
    float C0, float C1, float o[4])
{
    float xr[4];
#pragma unroll
    for (int j = 0; j < 4; ++j) {
        float a = b_in[j];
#pragma unroll
        for (int k = 0; k < 6; ++k) a = fmaf(W_in[j*6+k], xv[k], a);
        xr[j] = gelu_lut(a, s_lut);
    }
    float t[4];
#pragma unroll
    for (int j = 0; j < 4; ++j) {
        float L0 = 0.f, L1 = 0.f, bse = r_b[j];
#pragma unroll
        for (int k = 0; k < 4; ++k) {
            L0  = fmaf(cst[8  + j*4+k], xr[k], L0);
            L1  = fmaf(cst[24 + j*4+k], xr[k], L1);
            bse = fmaf(r_w[j*4+k],      xr[k], bse);
        }
        t[j] = fmaf(sin_rev(C0*L0), L0, fmaf(sin_rev(C1*L1), L1, bse));
    }
    const float mu = 0.25f * (t[0] + t[1] + t[2] + t[3]);
    float d0 = t[0]-mu, d1 = t[1]-mu, d2 = t[2]-mu, d3 = t[3]-mu;
    float var = fmaf(d0, d0, fmaf(d1, d1, fmaf(d2, d2, d3*d3)));
    const float inv = __builtin_amdgcn_rsqf(fmaf(0.25f, var, 1e-5f));
    float hr[4] = { gelu_lut(d0*inv, s_lut), gelu_lut(d1*inv, s_lut),
                    gelu_lut(d2*inv, s_lut), gelu_lut(d3*inv, s_lut) };
    float hid[8];
#pragma unroll
    for (int h = 0; h < 8; ++h) {
        float a = cst[72 + h];
#pragma unroll
        for (int j = 0; j < 4; ++j) a = fmaf(cst[40 + h*4+j], hr[j], a);
        hid[h] = gelu_lut(a, s_lut);
    }
#pragma unroll
    for (int oo = 0; oo < 4; ++oo) {
        float a = b_o2[oo];
#pragma unroll
        for (int h = 0; h < 8; ++h) a = fmaf(W_o2[oo*8+h], hid[h], a);
        o[oo] = a;
    }
}

// ==================== fused cooperative kernel (no state across sync) ================
__global__ __launch_bounds__(256, 6) void k_fused(
    const float* __restrict__ x,
    const float* __restrict__ W_in, const float* __restrict__ b_in,
    const float* __restrict__ r_w,  const float* __restrict__ r_b,
    const float* __restrict__ r_tf, const float* __restrict__ r_tc,
    const float* __restrict__ i_w,  const float* __restrict__ i_b,
    const float* __restrict__ i_tf, const float* __restrict__ i_tc,
    const float* __restrict__ W_ri, const float* __restrict__ b_ri,
    const float* __restrict__ W_ir, const float* __restrict__ b_ir,
    const float* __restrict__ flow_gate, const float* __restrict__ mem,
    const float* __restrict__ W_o1, const float* __restrict__ b_o1,
    const float* __restrict__ W_o2, const float* __restrict__ b_o2,
    float2* __restrict__ partials, float* __restrict__ cst,
    float* __restrict__ out, int B)
{
    const int tid = threadIdx.x;
    __shared__ float2 s_lut[LUT_N];
    __shared__ float s_red[8];
    __shared__ float s_c[2];
    __shared__ float s_hc[16], s_cv[4], s_m4[16];
    build_lut(s_lut, tid);

    if (blockIdx.x == 0) {
        fold_weights(tid, r_tf, r_tc, i_w, i_b, i_tf, i_tc, W_ri, b_ri, W_ir, b_ir,
                     flow_gate, mem, W_o1, b_o1, cst, s_hc, s_cv, s_m4);
    }
    __syncthreads();   // LUT ready

    // ---- phase B: batch sums ----
    const int npairs = B >> 1;
    const int TT = gridDim.x * blockDim.x;
    const int gtid = blockIdx.x * blockDim.x + tid;
    float s0 = 0.f, s1 = 0.f;

    for (int p = gtid; p < npairs; p += TT) {
        const float4* xp = (const float4*)(x + (size_t)p * 12);
        float4 q0 = xp[0], q1 = xp[1], q2 = xp[2];
        float xv[2][6] = {{q0.x, q0.y, q0.z, q0.w, q1.x, q1.y},
                          {q1.z, q1.w, q2.x, q2.y, q2.z, q2.w}};
#pragma unroll
        for (int r = 0; r < 2; ++r) {
            float xr[4];
#pragma unroll
            for (int j = 0; j < 4; ++j) {
                float a = b_in[j];
#pragma unroll
                for (int k = 0; k < 6; ++k) a = fmaf(W_in[j*6+k], xv[r][k], a);
                xr[j] = gelu_lut(a, s_lut);
            }
#pragma unroll
            for (int j = 0; j < 4; ++j) {
                float l0 = 0.f, l1 = 0.f;
#pragma unroll
                for (int k = 0; k < 4; ++k) {
                    l0 = fmaf(r_tf[j*4+k],      xr[k], l0);
                    l1 = fmaf(r_tf[16 + j*4+k], xr[k], l1);
                }
                s0 += fabsf(l0);
                s1 += fabsf(l1);
            }
        }
    }
    if ((B & 1) && gtid == 0) {
        const float* xs = x + (size_t)(B-1) * 6;
        float xr[4];
#pragma unroll
        for (int j = 0; j < 4; ++j) {
            float a = b_in[j];
#pragma unroll
            for (int k = 0; k < 6; ++k) a = fmaf(W_in[j*6+k], xs[k], a);
            xr[j] = gelu_lut(a, s_lut);
        }
#pragma unroll
        for (int j = 0; j < 4; ++j) {
            float l0 = 0.f, l1 = 0.f;
#pragma unroll
            for (int k = 0; k < 4; ++k) {
                l0 = fmaf(r_tf[j*4+k],      xr[k], l0);
                l1 = fmaf(r_tf[16 + j*4+k], xr[k], l1);
            }
            s0 += fabsf(l0);
            s1 += fabsf(l1);
        }
    }
#pragma unroll
    for (int off = 32; off > 0; off >>= 1) {
        s0 += __shfl_down(s0, off);
        s1 += __shfl_down(s1, off);
    }
    if ((tid & 63) == 0) { s_red[(tid>>6)*2] = s0; s_red[(tid>>6)*2+1] = s1; }
    __syncthreads();
    if (tid == 0) {
        partials[blockIdx.x] = make_float2(s_red[0]+s_red[2]+s_red[4]+s_red[6],
                                           s_red[1]+s_red[3]+s_red[5]+s_red[7]);
    }

    cg::this_grid().sync();

    // ---- phase C: redundant deterministic reduce (identical per block) ----
    float t0 = 0.f, t1 = 0.f;
    const int nb = (int)gridDim.x;
    for (int k = tid; k < nb; k += 256) {
        const float2 pr = partials[k];
        t0 += pr.x; t1 += pr.y;
    }
#pragma unroll
    for (int off = 32; off > 0; off >>= 1) {
        t0 += __shfl_down(t0, off);
        t1 += __shfl_down(t1, off);
    }
    __syncthreads();   // s_red reuse
    if ((tid & 63) == 0) { s_red[(tid>>6)*2] = t0; s_red[(tid>>6)*2+1] = t1; }
    __syncthreads();
    if (tid == 0) {
        const float sr = cst[2];
        const float u0 = s_red[0]+s_red[2]+s_red[4]+s_red[6];
        const float u1 = s_red[1]+s_red[3]+s_red[5]+s_red[7];
        const float m0 = u0 / (4.0f * (float)B);
        const float m1 = u1 / (4.0f * (float)B);
        s_c[0] = 1.0f / ((m0 + 1e-8f) * sr);   // revolution-domain
        s_c[1] = 4.0f / ((m1 + 1e-8f) * sr);
    }
    __syncthreads();
    const float C0 = s_c[0], C1 = s_c[1];

    // ---- phase D: per-row pipeline (round-8 k_main body) ----
    for (int p = gtid; p < npairs; p += TT) {
        const float4* xp = (const float4*)(x + (size_t)p * 12);
        float4 q0 = xp[0], q1 = xp[1], q2 = xp[2];
        float xv[2][6] = {{q0.x, q0.y, q0.z, q0.w, q1.x, q1.y},
                          {q1.z, q1.w, q2.x, q2.y, q2.z, q2.w}};
        float o2[2][4];
#pragma unroll
        for (int r = 0; r < 2; ++r)
            row_pipeline(xv[r], W_in, b_in, r_w, r_b, W_o2, b_o2, cst, s_lut,
                         C0, C1, o2[r]);
        typedef float v4f __attribute__((ext_vector_type(4)));
        v4f r0 = (v4f){ o2[0][0], o2[0][1], o2[0][2], o2[0][3] };
        v4f r1 = (v4f){ o2[1][0], o2[1][1], o2[1][2], o2[1][3] };
        __builtin_nontemporal_store(r0, (v4f*)out + (size_t)2*p);
        __builtin_nontemporal_store(r1, (v4f*)out + (size_t)2*p + 1);
    }
    if ((B & 1) && gtid == 0) {
        const float* xs = x + (size_t)(B-1) * 6;
        float xv[6];
#pragma unroll
        for (int k = 0; k < 6; ++k) xv[k] = xs[k];
        float o[4];
        row_pipeline(xv, W_in, b_in, r_w, r_b, W_o2, b_o2, cst, s_lut, C0, C1, o);
        ((float4*)out)[(size_t)B - 1] = make_float4(o[0], o[1], o[2], o[3]);
    }
}

// ==================== fallback: round-8 two-kernel path ====================
__global__ __launch_bounds__(256, 8) void k_sum(
    const float* __restrict__ x,
    const float* __restrict__ W_in, const float* __restrict__ b_in,
    const float* __restrict__ r_tf, const float* __restrict__ r_tc,
    const float* __restrict__ i_w,  const float* __restrict__ i_b,
    const float* __restrict__ i_tf, const float* __restrict__ i_tc,
    const float* __restrict__ W_ri, const float* __restrict__ b_ri,
    const float* __restrict__ W_ir, const float* __restrict__ b_ir,
    const float* __restrict__ flow_gate, const float* __restrict__ mem,
    const float* __restrict__ W_o1, const float* __restrict__ b_o1,
    float2* __restrict__ partials, float* __restrict__ cst, int B)
{
    const int tid = threadIdx.x;
    __shared__ float2 s_lut[LUT_N];
    __shared__ float s_red[8], s_hc[16], s_cv[4], s_m4[16];
    build_lut(s_lut, tid);
    if (blockIdx.x == 0) {
        fold_weights(tid, r_tf, r_tc, i_w, i_b, i_tf, i_tc, W_ri, b_ri, W_ir, b_ir,
                     flow_gate, mem, W_o1, b_o1, cst, s_hc, s_cv, s_m4);
    }
    __syncthreads();

    const int npairs = B >> 1;
    const int TT = gridDim.x * blockDim.x;
    const int gtid = blockIdx.x * blockDim.x + tid;
    float s0 = 0.f, s1 = 0.f;
    for (int p = gtid; p < npairs; p += TT) {
        const float4* xp = (const float4*)(x + (size_t)p * 12);
        float4 q0 = xp[0], q1 = xp[1], q2 = xp[2];
        float xv[2][6] = {{q0.x, q0.y, q0.z, q0.w, q1.x, q1.y},
                          {q1.z, q1.w, q2.x, q2.y, q2.z, q2.w}};
#pragma unroll
        for (int r = 0; r < 2; ++r) {
            float xr[4];
#pragma unroll
            for (int j = 0; j < 4; ++j) {
                float a = b_in[j];
#pragma unroll
                for (int k = 0; k < 6; ++k) a = fmaf(W_in[j*6+k], xv[r][k], a);
                xr[j] = gelu_lut(a, s_lut);
            }
#pragma unroll
            for (int j = 0; j < 4; ++j) {
                float l0 = 0.f, l1 = 0.f;
#pragma unroll
                for (int k = 0; k < 4; ++k) {
                    l0 = fmaf(r_tf[j*4+k],      xr[k], l0);
                    l1 = fmaf(r_tf[16 + j*4+k], xr[k], l1);
                }
                s0 += fabsf(l0);
                s1 += fabsf(l1);
            }
        }
    }
    if ((B & 1) && gtid == 0) {
        const float* xs = x + (size_t)(B-1) * 6;
        float xr[4];
#pragma unroll
        for (int j = 0; j < 4; ++j) {
            float a = b_in[j];
#pragma unroll
            for (int k = 0; k < 6; ++k) a = fmaf(W_in[j*6+k], xs[k], a);
            xr[j] = gelu_lut(a, s_lut);
        }
#pragma unroll
        for (int j = 0; j < 4; ++j) {
            float l0 = 0.f, l1 = 0.f;
#pragma unroll
            for (int k = 0; k < 4; ++k) {
                l0 = fmaf(r_tf[j*4+k],      xr[k], l0);
                l1 = fmaf(r_tf[16 + j*4+k], xr[k], l1);
            }
            s0 += fabsf(l0);
            s1 += fabsf(l1);
        }
    }
#pragma unroll
    for (int off = 32; off > 0; off >>= 1) {
        s0 += __shfl_down(s0, off);
        s1 += __shfl_down(s1, off);
    }
    if ((tid & 63) == 0) { s_red[(tid>>6)*2] = s0; s_red[(tid>>6)*2+1] = s1; }
    __syncthreads();
    if (tid == 0) {
        partials[blockIdx.x] = make_float2(s_red[0]+s_red[2]+s_red[4]+s_red[6],
                                           s_red[1]+s_red[3]+s_red[5]+s_red[7]);
    }
}

__global__ __launch_bounds__(256, 6) void k_main(
    const float* __restrict__ x,
    const float* __restrict__ W_in, const float* __restrict__ b_in,
    const float* __restrict__ r_w,  const float* __restrict__ r_b,
    const float* __restrict__ W_o2, const float* __restrict__ b_o2,
    const float2* __restrict__ partials, int nb,
    const float* __restrict__ cst,
    float* __restrict__ out, int B)
{
    const int tid = threadIdx.x;
    __shared__ float2 s_lut[LUT_N];
    __shared__ float s_red[8];
    __shared__ float s_c[2];
    build_lut(s_lut, tid);

    float t0 = 0.f, t1 = 0.f;
    for (int k = tid; k < nb; k += 256) {
        const float2 pr = partials[k];
        t0 += pr.x; t1 += pr.y;
    }
#pragma unroll
    for (int off = 32; off > 0; off >>= 1) {
        t0 += __shfl_down(t0, off);
        t1 += __shfl_down(t1, off);
    }
    if ((tid & 63) == 0) { s_red[(tid>>6)*2] = t0; s_red[(tid>>6)*2+1] = t1; }
    __syncthreads();
    if (tid == 0) {
        const float sr = cst[2];
        const float u0 = s_red[0]+s_red[2]+s_red[4]+s_red[6];
        const float u1 = s_red[1]+s_red[3]+s_red[5]+s_red[7];
        const float m0 = u0 / (4.0f * (float)B);
        const float m1 = u1 / (4.0f * (float)B);
        s_c[0] = 1.0f / ((m0 + 1e-8f) * sr);
        s_c[1] = 4.0f / ((m1 + 1e-8f) * sr);
    }
    __syncthreads();
    const float C0 = s_c[0], C1 = s_c[1];

    const int npairs = B >> 1;
    const int TT = gridDim.x * blockDim.x;
    const int gtid = blockIdx.x * blockDim.x + tid;

    for (int p = gtid; p < npairs; p += TT) {
        const float4* xp = (const float4*)(x + (size_t)p * 12);
        float4 q0 = xp[0], q1 = xp[1], q2 = xp[2];
        float xv[2][6] = {{q0.x, q0.y, q0.z, q0.w, q1.x, q1.y},
                          {q1.z, q1.w, q2.x, q2.y, q2.z, q2.w}};
        float o2[2][4];
#pragma unroll
        for (int r = 0; r < 2; ++r)
            row_pipeline(xv[r], W_in, b_in, r_w, r_b, W_o2, b_o2, cst, s_lut,
                         C0, C1, o2[r]);
        typedef float v4f __attribute__((ext_vector_type(4)));
        v4f r0 = (v4f){ o2[0][0], o2[0][1], o2[0][2], o2[0][3] };
        v4f r1 = (v4f){ o2[1][0], o2[1][1], o2[1][2], o2[1][3] };
        __builtin_nontemporal_store(r0, (v4f*)out + (size_t)2*p);
        __builtin_nontemporal_store(r1, (v4f*)out + (size_t)2*p + 1);
    }
    if ((B & 1) && gtid == 0) {
        const float* xs = x + (size_t)(B-1) * 6;
        float xv[6];
#pragma unroll
        for (int k = 0; k < 6; ++k) xv[k] = xs[k];
        float o[4];
        row_pipeline(xv, W_in, b_in, r_w, r_b, W_o2, b_o2, cst, s_lut, C0, C1, o);
        ((float4*)out)[(size_t)B - 1] = make_float4(o[0], o[1], o[2], o[3]);
    }
}

extern "C" void kernel_launch(void* const* d_in, const int* in_sizes, int n_in,
                              void* d_out, int out_size, void* d_ws, size_t ws_size,
                              hipStream_t stream)
{
    const float* x    = (const float*)d_in[0];
    const float* W_in = (const float*)d_in[1];
    const float* b_in = (const float*)d_in[2];
    const float* r_w  = (const float*)d_in[3];
    const float* r_b  = (const float*)d_in[4];
    const float* r_tf = (const float*)d_in[5];
    const float* r_tc = (const float*)d_in[6];
    const float* i_w  = (const float*)d_in[7];
    const float* i_b  = (const float*)d_in[8];
    const float* i_tf = (const float*)d_in[9];
    const float* i_tc = (const float*)d_in[10];
    const float* W_ri = (const float*)d_in[11];
    const float* b_ri = (const float*)d_in[12];
    const float* W_ir = (const float*)d_in[13];
    const float* b_ir = (const float*)d_in[14];
    const float* fg   = (const float*)d_in[15];
    const float* mem  = (const float*)d_in[16];
    const float* W_o1 = (const float*)d_in[17];
    const float* b_o1 = (const float*)d_in[18];
    const float* W_o2 = (const float*)d_in[19];
    const float* b_o2 = (const float*)d_in[20];
    float* out = (float*)d_out;
    float* ws  = (float*)d_ws;

    const int B = in_sizes[0] / 6;
    const int npairs = B >> 1;

    // ws layout (floats): [0..127] = cst, [128..] = partials (float2 per block)
    float*  cst      = ws;
    float2* partials = (float2*)(ws + 128);

    // ---- primary: fused cooperative kernel (1536 blocks = 6/CU, round-8 geometry) ----
    int NB = 1536;
    if (NB * 256 > npairs + 255) NB = (npairs + 255) / 256;
    if (NB < 1) NB = 1;
    const bool coop_ok = (ws_size >= (size_t)(128 + 2*NB + 2) * sizeof(float));

    if (coop_ok) {
        int Bv = B;
        void* args[] = {
            (void*)&x, (void*)&W_in, (void*)&b_in, (void*)&r_w, (void*)&r_b,
            (void*)&r_tf, (void*)&r_tc, (void*)&i_w, (void*)&i_b, (void*)&i_tf,
            (void*)&i_tc, (void*)&W_ri, (void*)&b_ri, (void*)&W_ir, (void*)&b_ir,
            (void*)&fg, (void*)&mem, (void*)&W_o1, (void*)&b_o1, (void*)&W_o2,
            (void*)&b_o2, (void*)&partials, (void*)&cst, (void*)&out, (void*)&Bv
        };
        hipError_t e = hipLaunchCooperativeKernel((void*)k_fused, dim3(NB), dim3(256),
                                                  args, 0, stream);
        if (e == hipSuccess) return;
    }

    // ---- fallback: round-8 two-kernel path ----
    int NB1 = 2048;
    const long cap = (long)(ws_size / 4) - 128;
    if (cap < 2L * NB1) NB1 = (int)(cap / 2);
    if (NB1 < 1) NB1 = 1;

    k_sum<<<NB1, 256, 0, stream>>>(x, W_in, b_in, r_tf, r_tc, i_w, i_b, i_tf, i_tc,
                                   W_ri, b_ri, W_ir, b_ir, fg, mem, W_o1, b_o1,
                                   partials, cst, B);
    int NB2 = 1536;
    if (NB2 * 256 > npairs + 255) NB2 = (npairs + 255) / 256;
    if (NB2 < 1) NB2 = 1;
    k_main<<<NB2, 256, 0, stream>>>(x, W_in, b_in, r_w, r_b, W_o2, b_o2,
                                    partials, NB1, cst, out, B);
}

// Round 12
// 43.254 us; speedup vs baseline: 6.4625x; 6.4625x over previous
//
#include <hip/hip_runtime.h>
#include <math.h>

#define TWO_PI_F 6.2831853071795864769f
#define LUT_N    2048
#define LUT_SCALE 170.66666667f   // 2048/12
#define LUT_STEP  0.005859375f    // 12/2048 (exact)

static __device__ __forceinline__ float sin_rev(float x) {   // sin(2*pi*x)
#if __has_builtin(__builtin_amdgcn_sinf)
    return __builtin_amdgcn_sinf(x);
#else
    return __sinf(TWO_PI_F * x);
#endif
}

// accurate branchless CDF: 0.5*(1+erf(x/sqrt2)), A&S 7.1.26 (|err|<=1.5e-7)
static __device__ __forceinline__ float cdf_acc(float v) {
    const float y  = v * 0.70710678118654752f;
    const float ay = fabsf(y);
    const float t  = __builtin_amdgcn_rcpf(fmaf(0.3275911f, ay, 1.0f));
    const float e  = __builtin_amdgcn_exp2f(y * y * -1.4426950408889634f);
    float p = fmaf(1.061405429f, t, -1.453152027f);
    p = fmaf(p, t, 1.421413741f);
    p = fmaf(p, t, -0.284496736f);
    p = fmaf(p, t, 0.254829592f);
    const float erf_abs = 1.0f - p * t * e;
    const float erf_v   = __builtin_copysignf(erf_abs, v);
    return fmaf(0.5f, erf_v, 0.5f);
}
static __device__ __forceinline__ float gelu_s(float v) { return v * cdf_acc(v); }

// LDS-LUT gelu: x * lerp(t_i, t_i+dt_i)
static __device__ __forceinline__ float gelu_lut(float x, const float2* __restrict__ lut) {
    float f = fminf(fmaxf(fmaf(x, LUT_SCALE, 1024.0f), 0.0f), 2047.5f);
    float ff = floorf(f);
    float fr = f - ff;
    float2 e = lut[(int)ff];
    return x * fmaf(fr, e.y, e.x);
}

static __device__ __forceinline__ void build_lut(float2* lut, int tid) {
    for (int i = tid; i < LUT_N; i += 256) {
        float x0 = fmaf((float)i, LUT_STEP, -6.0f);
        float t0 = cdf_acc(x0);
        float t1 = cdf_acc(x0 + LUT_STEP);
        lut[i] = make_float2(t0, t1 - t0);
    }
}

// cst layout: [2]=sr [8..23]=tfs0(sr*tf0) [24..39]=tfs1(0.5*sr*tf1)
//             [40..71]=W1e(8x4) [72..79]=b1e(8)
// ============ kernel 1: batch |lo| sums; block 0 folds weight-only constants ========
__global__ __launch_bounds__(256, 8) void k_sum(
    const float* __restrict__ x,
    const float* __restrict__ W_in, const float* __restrict__ b_in,
    const float* __restrict__ r_tf, const float* __restrict__ r_tc,
    const float* __restrict__ i_w,  const float* __restrict__ i_b,
    const float* __restrict__ i_tf, const float* __restrict__ i_tc,
    const float* __restrict__ W_ri, const float* __restrict__ b_ri,
    const float* __restrict__ W_ir, const float* __restrict__ b_ir,
    const float* __restrict__ flow_gate, const float* __restrict__ mem,
    const float* __restrict__ W_o1, const float* __restrict__ b_o1,
    float2* __restrict__ partials, float* __restrict__ cst, int B)
{
    const int tid = threadIdx.x;
    __shared__ float2 s_lut[LUT_N];
    __shared__ float s_red[8], s_hc[16], s_cv[4], s_m4[16];
    build_lut(s_lut, tid);

    if (blockIdx.x == 0) {
        // constant internal path (weights-only; no batch stats needed)
        if (tid < 64) {
            const int j = tid & 15;
            float base = i_b[j];
#pragma unroll
            for (int k = 0; k < 16; ++k) base = fmaf(i_w[j*16 + k], mem[k], base);
            float corr = 0.f;
#pragma unroll
            for (int n = 0; n < 3; ++n) {
                float lo = 0.f;
#pragma unroll
                for (int k = 0; k < 16; ++k) lo = fmaf(i_tf[n*256 + j*16 + k], mem[k], lo);
                float a = fabsf(lo);
                a += __shfl_xor(a, 1); a += __shfl_xor(a, 2);
                a += __shfl_xor(a, 4); a += __shfl_xor(a, 8);
                const float mean = a * (1.0f/16.0f);
                const float phase = TWO_PI_F * (float)(n+1) * lo / (mean + 1e-8f);
                corr = fmaf(sinf(phase), lo / (float)(n+1), corr);
            }
            const float sc = 1.0f / (1.0f + expf(-i_tc[0]));
            const float t = fmaf(sc, corr, base);
            float mu = t;
            mu += __shfl_xor(mu, 1); mu += __shfl_xor(mu, 2);
            mu += __shfl_xor(mu, 4); mu += __shfl_xor(mu, 8);
            mu *= (1.0f/16.0f);
            const float d = t - mu;
            float v = d*d;
            v += __shfl_xor(v, 1); v += __shfl_xor(v, 2);
            v += __shfl_xor(v, 4); v += __shfl_xor(v, 8);
            v *= (1.0f/16.0f);
            const float h = gelu_s(d * rsqrtf(v + 1e-5f));
            if (tid < 16) s_hc[j] = h;
        }
        __syncthreads();
        const float g  = 1.0f / (1.0f + expf(-flow_gate[0]));
        const float sr = 1.0f / (1.0f + expf(-r_tc[0]));
        if (tid < 4) {
            float acc = 0.f;
#pragma unroll
            for (int m = 0; m < 16; ++m)
                acc = fmaf(W_ir[tid*16 + m], fmaf(g, b_ri[m], s_hc[m]), acc);
            s_cv[tid] = g * (acc + b_ir[tid]);
        }
        if (tid < 16) {
            const int l = tid >> 2, j = tid & 3;
            float M = 0.f;
#pragma unroll
            for (int m = 0; m < 16; ++m) M = fmaf(W_ir[l*16 + m], W_ri[m*4 + j], M);
            s_m4[tid] = g * g * M;
            cst[8  + tid] = sr * r_tf[tid];             // tfs0
            cst[24 + tid] = 0.5f * sr * r_tf[16 + tid]; // tfs1
        }
        if (tid == 0) cst[2] = sr;
        __syncthreads();
        if (tid < 32) {   // W1e = W_o1 @ (I + M4)
            const int h = tid >> 2, j = tid & 3;
            float we = 0.f;
#pragma unroll
            for (int l = 0; l < 4; ++l)
                we = fmaf(W_o1[h*4 + l], ((l == j) ? 1.0f : 0.0f) + s_m4[l*4 + j], we);
            cst[40 + tid] = we;
        }
        if (tid < 8) {    // b1e = b_o1 + W_o1 @ cvec
            float be = b_o1[tid];
#pragma unroll
            for (int l = 0; l < 4; ++l) be = fmaf(W_o1[tid*4 + l], s_cv[l], be);
            cst[72 + tid] = be;
        }
    }
    __syncthreads();   // LUT ready (all blocks)

    const int npairs = B >> 1;
    const int TT = gridDim.x * blockDim.x;
    const int gtid = blockIdx.x * blockDim.x + tid;
    float s0 = 0.f, s1 = 0.f;

    for (int p = gtid; p < npairs; p += TT) {
        const float4* xp = (const float4*)(x + (size_t)p * 12);
        float4 q0 = xp[0], q1 = xp[1], q2 = xp[2];
        float xv[2][6] = {{q0.x, q0.y, q0.z, q0.w, q1.x, q1.y},
                          {q1.z, q1.w, q2.x, q2.y, q2.z, q2.w}};
#pragma unroll
        for (int r = 0; r < 2; ++r) {
            float xr[4];
#pragma unroll
            for (int j = 0; j < 4; ++j) {
                float a = b_in[j];
#pragma unroll
                for (int k = 0; k < 6; ++k) a = fmaf(W_in[j*6+k], xv[r][k], a);
                xr[j] = gelu_lut(a, s_lut);
            }
#pragma unroll
            for (int j = 0; j < 4; ++j) {
                float l0 = 0.f, l1 = 0.f;
#pragma unroll
                for (int k = 0; k < 4; ++k) {
                    l0 = fmaf(r_tf[j*4+k],      xr[k], l0);
                    l1 = fmaf(r_tf[16 + j*4+k], xr[k], l1);
                }
                s0 += fabsf(l0);
                s1 += fabsf(l1);
            }
        }
    }
    if ((B & 1) && gtid == 0) {
        const float* xs = x + (size_t)(B-1) * 6;
        float xr[4];
#pragma unroll
        for (int j = 0; j < 4; ++j) {
            float a = b_in[j];
#pragma unroll
            for (int k = 0; k < 6; ++k) a = fmaf(W_in[j*6+k], xs[k], a);
            xr[j] = gelu_lut(a, s_lut);
        }
#pragma unroll
        for (int j = 0; j < 4; ++j) {
            float l0 = 0.f, l1 = 0.f;
#pragma unroll
            for (int k = 0; k < 4; ++k) {
                l0 = fmaf(r_tf[j*4+k],      xr[k], l0);
                l1 = fmaf(r_tf[16 + j*4+k], xr[k], l1);
            }
            s0 += fabsf(l0);
            s1 += fabsf(l1);
        }
    }
#pragma unroll
    for (int off = 32; off > 0; off >>= 1) {
        s0 += __shfl_down(s0, off);
        s1 += __shfl_down(s1, off);
    }
    if ((tid & 63) == 0) { s_red[(tid>>6)*2] = s0; s_red[(tid>>6)*2+1] = s1; }
    __syncthreads();
    if (tid == 0) {
        partials[blockIdx.x] = make_float2(s_red[0]+s_red[2]+s_red[4]+s_red[6],
                                           s_red[1]+s_red[3]+s_red[5]+s_red[7]);
    }
}

// ============ kernel 2: per-block partial reduce (redundant) + per-row pipeline =====
__global__ __launch_bounds__(256, 6) void k_main(
    const float* __restrict__ x,
    const float* __restrict__ W_in, const float* __restrict__ b_in,
    const float* __restrict__ r_w,  const float* __restrict__ r_b,
    const float* __restrict__ W_o2, const float* __restrict__ b_o2,
    const float2* __restrict__ partials, int nb,
    const float* __restrict__ cst,
    float* __restrict__ out, int B)
{
    const int tid = threadIdx.x;
    __shared__ float2 s_lut[LUT_N];
    __shared__ float s_red[8];
    __shared__ float s_c[2];
    build_lut(s_lut, tid);

    // redundant deterministic reduce of block partials (identical result per block)
    float t0 = 0.f, t1 = 0.f;
    for (int k = tid; k < nb; k += 256) {
        const float2 pr = partials[k];
        t0 += pr.x; t1 += pr.y;
    }
#pragma unroll
    for (int off = 32; off > 0; off >>= 1) {
        t0 += __shfl_down(t0, off);
        t1 += __shfl_down(t1, off);
    }
    if ((tid & 63) == 0) { s_red[(tid>>6)*2] = t0; s_red[(tid>>6)*2+1] = t1; }
    __syncthreads();
    if (tid == 0) {
        const float sr = cst[2];
        const float u0 = s_red[0]+s_red[2]+s_red[4]+s_red[6];
        const float u1 = s_red[1]+s_red[3]+s_red[5]+s_red[7];
        const float m0 = u0 / (4.0f * (float)B);
        const float m1 = u1 / (4.0f * (float)B);
        s_c[0] = 1.0f / ((m0 + 1e-8f) * sr);   // revolution-domain
        s_c[1] = 4.0f / ((m1 + 1e-8f) * sr);
    }
    __syncthreads();
    const float C0 = s_c[0], C1 = s_c[1];

    const int npairs = B >> 1;
    const int TT = gridDim.x * blockDim.x;
    const int gtid = blockIdx.x * blockDim.x + tid;

    for (int p = gtid; p < npairs; p += TT) {
        const float4* xp = (const float4*)(x + (size_t)p * 12);
        float4 q0 = xp[0], q1 = xp[1], q2 = xp[2];
        float xv[2][6] = {{q0.x, q0.y, q0.z, q0.w, q1.x, q1.y},
                          {q1.z, q1.w, q2.x, q2.y, q2.z, q2.w}};
        float o2[2][4];
#pragma unroll
        for (int r = 0; r < 2; ++r) {
            float xr[4];
#pragma unroll
            for (int j = 0; j < 4; ++j) {
                float a = b_in[j];
#pragma unroll
                for (int k = 0; k < 6; ++k) a = fmaf(W_in[j*6+k], xv[r][k], a);
                xr[j] = gelu_lut(a, s_lut);
            }
            float t[4];
#pragma unroll
            for (int j = 0; j < 4; ++j) {
                float L0 = 0.f, L1 = 0.f, bse = r_b[j];
#pragma unroll
                for (int k = 0; k < 4; ++k) {
                    L0  = fmaf(cst[8  + j*4+k], xr[k], L0);
                    L1  = fmaf(cst[24 + j*4+k], xr[k], L1);
                    bse = fmaf(r_w[j*4+k],      xr[k], bse);
                }
                t[j] = fmaf(sin_rev(C0*L0), L0, fmaf(sin_rev(C1*L1), L1, bse));
            }
            const float mu = 0.25f * (t[0] + t[1] + t[2] + t[3]);
            float d0 = t[0]-mu, d1 = t[1]-mu, d2 = t[2]-mu, d3 = t[3]-mu;
            float var = fmaf(d0, d0, fmaf(d1, d1, fmaf(d2, d2, d3*d3)));
            const float inv = __builtin_amdgcn_rsqf(fmaf(0.25f, var, 1e-5f));
            float hr[4] = { gelu_lut(d0*inv, s_lut), gelu_lut(d1*inv, s_lut),
                            gelu_lut(d2*inv, s_lut), gelu_lut(d3*inv, s_lut) };

            float hid[8];
#pragma unroll
            for (int h = 0; h < 8; ++h) {
                float a = cst[72 + h];
#pragma unroll
                for (int j = 0; j < 4; ++j) a = fmaf(cst[40 + h*4+j], hr[j], a);
                hid[h] = gelu_lut(a, s_lut);
            }
#pragma unroll
            for (int oo = 0; oo < 4; ++oo) {
                float a = b_o2[oo];
#pragma unroll
                for (int h = 0; h < 8; ++h) a = fmaf(W_o2[oo*8+h], hid[h], a);
                o2[r][oo] = a;
            }
        }
        typedef float v4f __attribute__((ext_vector_type(4)));
        v4f r0 = (v4f){ o2[0][0], o2[0][1], o2[0][2], o2[0][3] };
        v4f r1 = (v4f){ o2[1][0], o2[1][1], o2[1][2], o2[1][3] };
        __builtin_nontemporal_store(r0, (v4f*)out + (size_t)2*p);
        __builtin_nontemporal_store(r1, (v4f*)out + (size_t)2*p + 1);
    }

    if ((B & 1) && gtid == 0) {   // tail row
        const float* xs = x + (size_t)(B-1) * 6;
        float xr[4];
#pragma unroll
        for (int j = 0; j < 4; ++j) {
            float a = b_in[j];
#pragma unroll
            for (int k = 0; k < 6; ++k) a = fmaf(W_in[j*6+k], xs[k], a);
            xr[j] = gelu_lut(a, s_lut);
        }
        float t[4];
#pragma unroll
        for (int j = 0; j < 4; ++j) {
            float L0 = 0.f, L1 = 0.f, bse = r_b[j];
#pragma unroll
            for (int k = 0; k < 4; ++k) {
                L0  = fmaf(cst[8  + j*4+k], xr[k], L0);
                L1  = fmaf(cst[24 + j*4+k], xr[k], L1);
                bse = fmaf(r_w[j*4+k],      xr[k], bse);
            }
            t[j] = fmaf(sin_rev(C0*L0), L0, fmaf(sin_rev(C1*L1), L1, bse));
        }
        const float mu = 0.25f * (t[0]+t[1]+t[2]+t[3]);
        float d0=t[0]-mu, d1=t[1]-mu, d2=t[2]-mu, d3=t[3]-mu;
        const float var = 0.25f * (d0*d0 + d1*d1 + d2*d2 + d3*d3);
        const float inv = __builtin_amdgcn_rsqf(var + 1e-5f);
        float hr[4] = { gelu_lut(d0*inv, s_lut), gelu_lut(d1*inv, s_lut),
                        gelu_lut(d2*inv, s_lut), gelu_lut(d3*inv, s_lut) };
        float hid[8];
#pragma unroll
        for (int h = 0; h < 8; ++h) {
            float a = cst[72 + h];
#pragma unroll
            for (int j = 0; j < 4; ++j) a = fmaf(cst[40 + h*4+j], hr[j], a);
            hid[h] = gelu_lut(a, s_lut);
        }
        float o[4];
#pragma unroll
        for (int oo = 0; oo < 4; ++oo) {
            float a = b_o2[oo];
#pragma unroll
            for (int h = 0; h < 8; ++h) a = fmaf(W_o2[oo*8+h], hid[h], a);
            o[oo] = a;
        }
        ((float4*)out)[(size_t)B - 1] = make_float4(o[0], o[1], o[2], o[3]);
    }
}

extern "C" void kernel_launch(void* const* d_in, const int* in_sizes, int n_in,
                              void* d_out, int out_size, void* d_ws, size_t ws_size,
                              hipStream_t stream)
{
    const float* x    = (const float*)d_in[0];
    const float* W_in = (const float*)d_in[1];
    const float* b_in = (const float*)d_in[2];
    const float* r_w  = (const float*)d_in[3];
    const float* r_b  = (const float*)d_in[4];
    const float* r_tf = (const float*)d_in[5];
    const float* r_tc = (const float*)d_in[6];
    const float* i_w  = (const float*)d_in[7];
    const float* i_b  = (const float*)d_in[8];
    const float* i_tf = (const float*)d_in[9];
    const float* i_tc = (const float*)d_in[10];
    const float* W_ri = (const float*)d_in[11];
    const float* b_ri = (const float*)d_in[12];
    const float* W_ir = (const float*)d_in[13];
    const float* b_ir = (const float*)d_in[14];
    const float* fg   = (const float*)d_in[15];
    const float* mem  = (const float*)d_in[16];
    const float* W_o1 = (const float*)d_in[17];
    const float* b_o1 = (const float*)d_in[18];
    const float* W_o2 = (const float*)d_in[19];
    const float* b_o2 = (const float*)d_in[20];
    float* out = (float*)d_out;
    float* ws  = (float*)d_ws;

    const int B = in_sizes[0] / 6;
    const int npairs = B >> 1;

    // ws layout (floats): [0..127] = cst, [128..] = partials (float2 per k_sum block)
    int NB1 = 2048;                       // 8 blocks/CU; npairs % (NB1*256) == 0 -> uniform
    const long cap = (long)(ws_size / 4) - 128;
    if (cap < 2L * NB1) NB1 = (int)(cap / 2);
    if (NB1 < 1) NB1 = 1;
    float*  cst      = ws;
    float2* partials = (float2*)(ws + 128);

    k_sum<<<NB1, 256, 0, stream>>>(x, W_in, b_in, r_tf, r_tc, i_w, i_b, i_tf, i_tc,
                                   W_ri, b_ri, W_ir, b_ir, fg, mem, W_o1, b_o1,
                                   partials, cst, B);

    int NB2 = 1536;                       // 6 blocks/CU co-resident
    if (NB2 * 256 > npairs + 255) NB2 = (npairs + 255) / 256;
    if (NB2 < 1) NB2 = 1;
    k_main<<<NB2, 256, 0, stream>>>(x, W_in, b_in, r_w, r_b, W_o2, b_o2,
                                    partials, NB1, cst, out, B);
}